// Round 1
// baseline (23059.631 us; speedup 1.0000x reference)
//
#include <hip/hip_runtime.h>
#include <math.h>

namespace {

constexpr int Bn = 512;
constexpr int Ln = 100;
constexpr int En = 256;
constexpr int Hn = 256;
constexpr int Tn = 100;

__device__ __forceinline__ float sigmf(float x) { return 1.0f / (1.0f + expf(-x)); }

// ---------------------------------------------------------------- init
__global__ void init_kernel(const float* __restrict__ dec, const float* __restrict__ h0,
                            const float* __restrict__ c0, float* __restrict__ x,
                            float* __restrict__ h, float* __restrict__ c,
                            int* __restrict__ mask, int* __restrict__ prev) {
  int i = blockIdx.x * 256 + threadIdx.x;
  if (i < Bn * En) x[i] = dec[i];
  if (i < Bn * Hn) { h[i] = h0[i]; c[i] = c0[i]; }
  if (i < Bn * Ln) mask[i] = 0;
  if (i < Bn) prev[i] = 0;
}

// ------------------------------------------------------- 256x256 transpose
__global__ void transpose256_kernel(const float* __restrict__ W, float* __restrict__ WT) {
  int h = blockIdx.x, k = threadIdx.x;
  WT[k * 256 + h] = W[h * 256 + k];
}

// ------------------------------------------------- e = Wref @ ctx + bref
// e_out[b,h,l] = sum_k WT[k,h]*context[l,b,k] + bref[h]
__global__ __launch_bounds__(256) void precompute_e_kernel(
    const float* __restrict__ WT, const float* __restrict__ bref,
    const float* __restrict__ context, float* __restrict__ e_out) {
  int b = blockIdx.x;           // 0..511
  int l0 = blockIdx.y * 25;     // 4 chunks of 25
  int h = threadIdx.x;          // 0..255
  __shared__ float ctx_s[25][256];
  for (int li = 0; li < 25; ++li)
    ctx_s[li][h] = context[((size_t)(l0 + li) * Bn + b) * Hn + h];
  __syncthreads();
  float acc[25];
  float bias = bref[h];
#pragma unroll
  for (int li = 0; li < 25; ++li) acc[li] = bias;
  for (int k = 0; k < 256; ++k) {
    float w = WT[k * 256 + h];
#pragma unroll
    for (int li = 0; li < 25; ++li) acc[li] += w * ctx_s[li][k];
  }
  float* ep = e_out + ((size_t)b * Hn + h) * Ln + l0;
#pragma unroll
  for (int li = 0; li < 25; ++li) ep[li] = acc[li];
}

// ------------------------------------------- LSTM gates GEMM + cell update
// gates[b, g*256+nn] = x[b,:]@Wi[g*256+nn,:] + h[b,:]@Wh[g*256+nn,:] + bi + bh
// tile: 32 batches x 16 cols x 4 gates; thread: 2 batches x 1 col x 4 gates
__global__ __launch_bounds__(256) void lstm_kernel(
    const float* __restrict__ x, const float* __restrict__ h_in,
    const float* __restrict__ c_in, const float* __restrict__ Wi,
    const float* __restrict__ Wh, const float* __restrict__ bi,
    const float* __restrict__ bh, float* __restrict__ h_out,
    float* __restrict__ c_out) {
  const int b0 = blockIdx.x * 32;
  const int n0 = blockIdx.y * 16;
  const int tid = threadIdx.x;
  const int n = tid & 15;
  const int br = tid >> 4;
  __shared__ float A_s[32][33];      // [kk][bb], pad -> 2-way max (free)
  __shared__ float W_s[4][16][33];   // [g][n][kk]
  float acc[4][2];
  const int nn = n0 + n;
#pragma unroll
  for (int g = 0; g < 4; ++g) {
    float bias = bi[g * 256 + nn] + bh[g * 256 + nn];
    acc[g][0] = bias;
    acc[g][1] = bias;
  }
  const int bb = tid >> 3, q = tid & 7;
  for (int k0 = 0; k0 < 512; k0 += 32) {
    const float* Asrc = (k0 < 256) ? x : h_in;
    const float* Wsrc = (k0 < 256) ? Wi : Wh;
    const int kb = k0 & 255;
    __syncthreads();
    float4 av = *(const float4*)(Asrc + (b0 + bb) * 256 + kb + q * 4);
    A_s[q * 4 + 0][bb] = av.x;
    A_s[q * 4 + 1][bb] = av.y;
    A_s[q * 4 + 2][bb] = av.z;
    A_s[q * 4 + 3][bb] = av.w;
#pragma unroll
    for (int s = 0; s < 2; ++s) {
      int sl = tid + s * 256;          // 512 float4 slots: [g][nl][q]
      int g = sl >> 7;
      int nl = (sl >> 3) & 15;
      int qq = sl & 7;
      float4 wv = *(const float4*)(Wsrc + ((g * 256 + n0 + nl) * 256) + kb + qq * 4);
      W_s[g][nl][qq * 4 + 0] = wv.x;
      W_s[g][nl][qq * 4 + 1] = wv.y;
      W_s[g][nl][qq * 4 + 2] = wv.z;
      W_s[g][nl][qq * 4 + 3] = wv.w;
    }
    __syncthreads();
#pragma unroll
    for (int kk = 0; kk < 32; ++kk) {
      float a0 = A_s[kk][2 * br];
      float a1 = A_s[kk][2 * br + 1];
#pragma unroll
      for (int g = 0; g < 4; ++g) {
        float w = W_s[g][n][kk];
        acc[g][0] += a0 * w;
        acc[g][1] += a1 * w;
      }
    }
  }
#pragma unroll
  for (int m = 0; m < 2; ++m) {
    int b = b0 + 2 * br + m;
    float ig = acc[0][m], fg = acc[1][m], cg = acc[2][m], og = acc[3][m];
    float cold = c_in[b * 256 + nn];
    float cy = sigmf(fg) * cold + sigmf(ig) * tanhf(cg);
    float hy = sigmf(og) * tanhf(cy);
    c_out[b * 256 + nn] = cy;
    h_out[b * 256 + nn] = hy;
  }
}

// ---------------------------------------------------- qp = A @ Wq^T + bq
__global__ __launch_bounds__(256) void qp_gemm_kernel(
    const float* __restrict__ A, const float* __restrict__ Wq,
    const float* __restrict__ bq, float* __restrict__ C) {
  const int b0 = blockIdx.x * 32;
  const int n0 = blockIdx.y * 16;
  const int tid = threadIdx.x;
  const int n = tid & 15;
  const int br = tid >> 4;
  __shared__ float A_s[32][33];
  __shared__ float W_s[16][33];
  float bias = bq[n0 + n];
  float acc0 = bias, acc1 = bias;
  const int bb = tid >> 3, q = tid & 7;
  for (int k0 = 0; k0 < 256; k0 += 32) {
    __syncthreads();
    float4 av = *(const float4*)(A + (b0 + bb) * 256 + k0 + q * 4);
    A_s[q * 4 + 0][bb] = av.x;
    A_s[q * 4 + 1][bb] = av.y;
    A_s[q * 4 + 2][bb] = av.z;
    A_s[q * 4 + 3][bb] = av.w;
    if (tid < 128) {
      int nl = tid >> 3, qq = tid & 7;
      float4 wv = *(const float4*)(Wq + (n0 + nl) * 256 + k0 + qq * 4);
      W_s[nl][qq * 4 + 0] = wv.x;
      W_s[nl][qq * 4 + 1] = wv.y;
      W_s[nl][qq * 4 + 2] = wv.z;
      W_s[nl][qq * 4 + 3] = wv.w;
    }
    __syncthreads();
#pragma unroll
    for (int kk = 0; kk < 32; ++kk) {
      float a0 = A_s[kk][2 * br];
      float a1 = A_s[kk][2 * br + 1];
      float w = W_s[n][kk];
      acc0 += a0 * w;
      acc1 += a1 * w;
    }
  }
  C[(b0 + 2 * br) * 256 + n0 + n] = acc0;
  C[(b0 + 2 * br + 1) * 256 + n0 + n] = acc1;
}

// -------------------------------------------------------- glimpse attention
// per block: 2 batches (grp 0/1, 128 threads each)
__global__ __launch_bounds__(256) void glimpse_kernel(
    const float* __restrict__ qp, const float* __restrict__ v,
    const float* __restrict__ e, int* __restrict__ mask,
    const int* __restrict__ prev, float* __restrict__ gl, int step) {
  const int tid = threadIdx.x;
  const int grp = tid >> 7;
  const int ti = tid & 127;
  const int b = blockIdx.x * 2 + grp;
  __shared__ float qp_s[2][256];
  __shared__ float v_s[256];
  __shared__ float p_s[2][128];
  __shared__ float red[2][128];
  qp_s[0][tid] = qp[(blockIdx.x * 2 + 0) * 256 + tid];
  qp_s[1][tid] = qp[(blockIdx.x * 2 + 1) * 256 + tid];
  v_s[tid] = v[tid];
  __syncthreads();
  const int l = ti;
  float lgv = -INFINITY;
  if (l < Ln) {
    float a = 0.0f;
    const float* ep = e + (size_t)b * Hn * Ln + l;
#pragma unroll 4
    for (int h = 0; h < Hn; ++h) a += v_s[h] * tanhf(qp_s[grp][h] + ep[(size_t)h * Ln]);
    int pb = prev[b];
    int mi = b * Ln + l;
    int m = mask[mi];
    if (step == 0) {
      if (l == 0) m = 1;
    } else {
      if (step == 1 && l == 0) m = 0;
      if (l == pb) m = 1;
    }
    mask[mi] = m;   // pointer-phase apply_mask is idempotent on this
    lgv = m ? -INFINITY : a;
  }
  red[grp][ti] = lgv;
  __syncthreads();
  for (int off = 64; off > 0; off >>= 1) {
    if (ti < off) red[grp][ti] = fmaxf(red[grp][ti], red[grp][ti + off]);
    __syncthreads();
  }
  float mx = red[grp][0];
  __syncthreads();
  float pvv = (lgv == -INFINITY) ? 0.0f : expf(lgv - mx);
  red[grp][ti] = pvv;
  __syncthreads();
  for (int off = 64; off > 0; off >>= 1) {
    if (ti < off) red[grp][ti] += red[grp][ti + off];
    __syncthreads();
  }
  float tot = red[grp][0];
  p_s[grp][ti] = pvv / tot;
  __syncthreads();
  // readout: gl[b,h] = sum_l e[b,h,l] * p[l]
  for (int hh = ti; hh < Hn; hh += 128) {
    const float* er = e + ((size_t)b * Hn + hh) * Ln;
    float a = 0.0f;
#pragma unroll 4
    for (int ll = 0; ll < Ln; ++ll) a += er[ll] * p_s[grp][ll];
    gl[b * Hn + hh] = a;
  }
}

// -------------------------------------------------------- pointer attention
__global__ __launch_bounds__(256) void pointer_kernel(
    const float* __restrict__ qp, const float* __restrict__ v,
    const float* __restrict__ e, const int* __restrict__ mask,
    int* __restrict__ prev, const float* __restrict__ emb,
    float* __restrict__ xout, float* __restrict__ out, int step) {
  const int tid = threadIdx.x;
  const int grp = tid >> 7;
  const int ti = tid & 127;
  const int b = blockIdx.x * 2 + grp;
  __shared__ float qp_s[2][256];
  __shared__ float v_s[256];
  __shared__ float red[2][128];
  __shared__ int ridx[2][128];
  __shared__ int sel_s[2];
  qp_s[0][tid] = qp[(blockIdx.x * 2 + 0) * 256 + tid];
  qp_s[1][tid] = qp[(blockIdx.x * 2 + 1) * 256 + tid];
  v_s[tid] = v[tid];
  __syncthreads();
  const int l = ti;
  float lgv = -INFINITY;
  if (l < Ln) {
    float a = 0.0f;
    const float* ep = e + (size_t)b * Hn * Ln + l;
#pragma unroll 4
    for (int h = 0; h < Hn; ++h) a += v_s[h] * tanhf(qp_s[grp][h] + ep[(size_t)h * Ln]);
    float lp = 10.0f * tanhf(a);
    int m = mask[b * Ln + l];    // already updated by glimpse this step
    lgv = m ? -INFINITY : lp;
  }
  red[grp][ti] = lgv;
  __syncthreads();
  for (int off = 64; off > 0; off >>= 1) {
    if (ti < off) red[grp][ti] = fmaxf(red[grp][ti], red[grp][ti + off]);
    __syncthreads();
  }
  float mx = red[grp][0];
  __syncthreads();
  float pvv = (lgv == -INFINITY) ? 0.0f : expf(lgv - mx);
  red[grp][ti] = pvv;
  __syncthreads();
  for (int off = 64; off > 0; off >>= 1) {
    if (ti < off) red[grp][ti] += red[grp][ti + off];
    __syncthreads();
  }
  float tot = red[grp][0];
  float p = pvv / tot;
  if (l < Ln) out[((size_t)step * Bn + b) * Ln + l] = p;
  __syncthreads();
  // argmax over p, first-index tie-break (mirrors jnp.argmax(softmax))
  red[grp][ti] = (l < Ln) ? p : -1.0f;
  ridx[grp][ti] = l;
  __syncthreads();
  for (int off = 64; off > 0; off >>= 1) {
    if (ti < off) {
      float ov = red[grp][ti + off];
      int oi = ridx[grp][ti + off];
      if (ov > red[grp][ti] || (ov == red[grp][ti] && oi < ridx[grp][ti])) {
        red[grp][ti] = ov;
        ridx[grp][ti] = oi;
      }
    }
    __syncthreads();
  }
  if (ti == 0) {
    int sel = ridx[grp][0];
    sel_s[grp] = sel;
    out[(size_t)Tn * Bn * Ln + (size_t)step * Bn + b] = (float)sel;
    prev[b] = sel;
  }
  __syncthreads();
  int sel = sel_s[grp];
  for (int ee = ti; ee < En; ee += 128)
    xout[b * En + ee] = emb[((size_t)sel * Bn + b) * En + ee];
}

// ---------------------------------------------------------------- finalize
__global__ void finalize_kernel(const float* __restrict__ h,
                                const float* __restrict__ c,
                                float* __restrict__ out) {
  int i = blockIdx.x * 256 + threadIdx.x;
  const size_t base = (size_t)Tn * Bn * Ln + (size_t)Tn * Bn;
  if (i < Bn * Hn) {
    out[base + i] = h[i];
    out[base + (size_t)Bn * Hn + i] = c[i];
  }
}

}  // namespace

extern "C" void kernel_launch(void* const* d_in, const int* in_sizes, int n_in,
                              void* d_out, int out_size, void* d_ws, size_t ws_size,
                              hipStream_t stream) {
  (void)in_sizes; (void)n_in; (void)out_size; (void)ws_size;
  const float* dec   = (const float*)d_in[0];
  const float* emb   = (const float*)d_in[1];
  const float* h0    = (const float*)d_in[2];
  const float* c0    = (const float*)d_in[3];
  const float* ctx   = (const float*)d_in[4];
  const float* Wi    = (const float*)d_in[5];
  const float* bi    = (const float*)d_in[6];
  const float* Wh    = (const float*)d_in[7];
  const float* bh    = (const float*)d_in[8];
  const float* gWq   = (const float*)d_in[9];
  const float* gbq   = (const float*)d_in[10];
  const float* gWref = (const float*)d_in[11];
  const float* gbref = (const float*)d_in[12];
  const float* gv    = (const float*)d_in[13];
  const float* pWq   = (const float*)d_in[14];
  const float* pbq   = (const float*)d_in[15];
  const float* pWref = (const float*)d_in[16];
  const float* pbref = (const float*)d_in[17];
  const float* pv    = (const float*)d_in[18];

  float* ws = (float*)d_ws;
  float* e_g   = ws;  ws += (size_t)Bn * Hn * Ln;
  float* e_p   = ws;  ws += (size_t)Bn * Hn * Ln;
  float* WTg   = ws;  ws += 256 * 256;
  float* WTp   = ws;  ws += 256 * 256;
  float* xbuf  = ws;  ws += Bn * En;
  float* hbuf  = ws;  ws += 2 * Bn * Hn;
  float* cbuf  = ws;  ws += 2 * Bn * Hn;
  float* qpg   = ws;  ws += Bn * Hn;
  float* qpp   = ws;  ws += Bn * Hn;
  float* glbuf = ws;  ws += Bn * Hn;
  int* maskb   = (int*)ws;  ws += Bn * Ln;
  int* prevb   = (int*)ws;  ws += Bn;
  float* out = (float*)d_out;

  init_kernel<<<512, 256, 0, stream>>>(dec, h0, c0, xbuf, hbuf, cbuf, maskb, prevb);
  transpose256_kernel<<<256, 256, 0, stream>>>(gWref, WTg);
  transpose256_kernel<<<256, 256, 0, stream>>>(pWref, WTp);
  precompute_e_kernel<<<dim3(512, 4), 256, 0, stream>>>(WTg, gbref, ctx, e_g);
  precompute_e_kernel<<<dim3(512, 4), 256, 0, stream>>>(WTp, pbref, ctx, e_p);

  for (int t = 0; t < Tn; ++t) {
    const float* hin = hbuf + (t & 1) * Bn * Hn;
    float* hout      = hbuf + ((t + 1) & 1) * Bn * Hn;
    const float* cin = cbuf + (t & 1) * Bn * Hn;
    float* cout      = cbuf + ((t + 1) & 1) * Bn * Hn;
    lstm_kernel<<<dim3(16, 16), 256, 0, stream>>>(xbuf, hin, cin, Wi, Wh, bi, bh, hout, cout);
    qp_gemm_kernel<<<dim3(16, 16), 256, 0, stream>>>(hout, gWq, gbq, qpg);
    glimpse_kernel<<<256, 256, 0, stream>>>(qpg, gv, e_g, maskb, prevb, glbuf, t);
    qp_gemm_kernel<<<dim3(16, 16), 256, 0, stream>>>(glbuf, pWq, pbq, qpp);
    pointer_kernel<<<256, 256, 0, stream>>>(qpp, pv, e_p, maskb, prevb, emb, xbuf, out, t);
  }
  finalize_kernel<<<512, 256, 0, stream>>>(hbuf, cbuf, out);
}

// Round 2
// 9480.627 us; speedup vs baseline: 2.4323x; 2.4323x over previous
//
#include <hip/hip_runtime.h>
#include <math.h>

namespace {

constexpr int Bn = 512;
constexpr int Ln = 100;
constexpr int En = 256;
constexpr int Hn = 256;
constexpr int Tn = 100;

// fast tanh: sign(x) * (1 - e^{-2|x|}) / (1 + e^{-2|x|});  ~3e-8 abs error
__device__ __forceinline__ float fast_tanh(float x) {
  float ax = fabsf(x);
  float e = __expf(-2.0f * ax);
  float t = (1.0f - e) / (1.0f + e);
  return copysignf(t, x);
}
__device__ __forceinline__ float fast_sigm(float x) {
  return 1.0f / (1.0f + __expf(-x));
}

__device__ __forceinline__ float wave_max(float v) {
#pragma unroll
  for (int off = 32; off > 0; off >>= 1) v = fmaxf(v, __shfl_xor(v, off, 64));
  return v;
}
__device__ __forceinline__ float wave_sum(float v) {
#pragma unroll
  for (int off = 32; off > 0; off >>= 1) v += __shfl_xor(v, off, 64);
  return v;
}

// ---------------------------------------------------------------- init
__global__ void init_kernel(const float* __restrict__ dec, const float* __restrict__ h0,
                            const float* __restrict__ c0, float* __restrict__ x,
                            float* __restrict__ h, float* __restrict__ c,
                            int* __restrict__ mask, int* __restrict__ prev) {
  int i = blockIdx.x * 256 + threadIdx.x;
  if (i < Bn * En) x[i] = dec[i];
  if (i < Bn * Hn) { h[i] = h0[i]; c[i] = c0[i]; }
  if (i < Bn * Ln) mask[i] = 0;
  if (i < Bn) prev[i] = 0;
}

// ------------------------------------------------------- 256x256 transpose
__global__ void transpose256_kernel(const float* __restrict__ W, float* __restrict__ WT) {
  int h = blockIdx.x, k = threadIdx.x;
  WT[k * 256 + h] = W[h * 256 + k];
}

// ------------------------------------------------- e_t[b][l][h] = (Wref @ ctx)[b,h,l] + bref[h]
__global__ __launch_bounds__(256) void precompute_e_kernel(
    const float* __restrict__ WT, const float* __restrict__ bref,
    const float* __restrict__ context, float* __restrict__ e_t) {
  int b = blockIdx.x;           // 0..511
  int l0 = blockIdx.y * 25;     // 4 chunks of 25
  int h = threadIdx.x;          // 0..255
  __shared__ float ctx_s[25][256];
  for (int li = 0; li < 25; ++li)
    ctx_s[li][h] = context[((size_t)(l0 + li) * Bn + b) * Hn + h];
  __syncthreads();
  float acc[25];
  float bias = bref[h];
#pragma unroll
  for (int li = 0; li < 25; ++li) acc[li] = bias;
  for (int k = 0; k < 256; ++k) {
    float w = WT[k * 256 + h];
#pragma unroll
    for (int li = 0; li < 25; ++li) acc[li] += w * ctx_s[li][k];
  }
#pragma unroll
  for (int li = 0; li < 25; ++li)
    e_t[((size_t)b * Ln + (l0 + li)) * Hn + h] = acc[li];   // lanes h: coalesced
}

// ------------------------------------------- LSTM gates GEMM + cell update
__global__ __launch_bounds__(256) void lstm_kernel(
    const float* __restrict__ x, const float* __restrict__ h_in,
    const float* __restrict__ c_in, const float* __restrict__ Wi,
    const float* __restrict__ Wh, const float* __restrict__ bi,
    const float* __restrict__ bh, float* __restrict__ h_out,
    float* __restrict__ c_out) {
  const int b0 = blockIdx.x * 32;
  const int n0 = blockIdx.y * 16;
  const int tid = threadIdx.x;
  const int n = tid & 15;
  const int br = tid >> 4;
  __shared__ float A_s[32][33];
  __shared__ float W_s[4][16][33];
  float acc[4][2];
  const int nn = n0 + n;
#pragma unroll
  for (int g = 0; g < 4; ++g) {
    float bias = bi[g * 256 + nn] + bh[g * 256 + nn];
    acc[g][0] = bias;
    acc[g][1] = bias;
  }
  const int bb = tid >> 3, q = tid & 7;
  for (int k0 = 0; k0 < 512; k0 += 32) {
    const float* Asrc = (k0 < 256) ? x : h_in;
    const float* Wsrc = (k0 < 256) ? Wi : Wh;
    const int kb = k0 & 255;
    __syncthreads();
    float4 av = *(const float4*)(Asrc + (b0 + bb) * 256 + kb + q * 4);
    A_s[q * 4 + 0][bb] = av.x;
    A_s[q * 4 + 1][bb] = av.y;
    A_s[q * 4 + 2][bb] = av.z;
    A_s[q * 4 + 3][bb] = av.w;
#pragma unroll
    for (int s = 0; s < 2; ++s) {
      int sl = tid + s * 256;
      int g = sl >> 7;
      int nl = (sl >> 3) & 15;
      int qq = sl & 7;
      float4 wv = *(const float4*)(Wsrc + ((g * 256 + n0 + nl) * 256) + kb + qq * 4);
      W_s[g][nl][qq * 4 + 0] = wv.x;
      W_s[g][nl][qq * 4 + 1] = wv.y;
      W_s[g][nl][qq * 4 + 2] = wv.z;
      W_s[g][nl][qq * 4 + 3] = wv.w;
    }
    __syncthreads();
#pragma unroll
    for (int kk = 0; kk < 32; ++kk) {
      float a0 = A_s[kk][2 * br];
      float a1 = A_s[kk][2 * br + 1];
#pragma unroll
      for (int g = 0; g < 4; ++g) {
        float w = W_s[g][n][kk];
        acc[g][0] += a0 * w;
        acc[g][1] += a1 * w;
      }
    }
  }
#pragma unroll
  for (int m = 0; m < 2; ++m) {
    int b = b0 + 2 * br + m;
    float ig = acc[0][m], fg = acc[1][m], cg = acc[2][m], og = acc[3][m];
    float cold = c_in[b * 256 + nn];
    float cy = fast_sigm(fg) * cold + fast_sigm(ig) * fast_tanh(cg);
    float hy = fast_sigm(og) * fast_tanh(cy);
    c_out[b * 256 + nn] = cy;
    h_out[b * 256 + nn] = hy;
  }
}

// ---------------------------------------------------- qp = A @ Wq^T + bq
__global__ __launch_bounds__(256) void qp_gemm_kernel(
    const float* __restrict__ A, const float* __restrict__ Wq,
    const float* __restrict__ bq, float* __restrict__ C) {
  const int b0 = blockIdx.x * 32;
  const int n0 = blockIdx.y * 16;
  const int tid = threadIdx.x;
  const int n = tid & 15;
  const int br = tid >> 4;
  __shared__ float A_s[32][33];
  __shared__ float W_s[16][33];
  float bias = bq[n0 + n];
  float acc0 = bias, acc1 = bias;
  const int bb = tid >> 3, q = tid & 7;
  for (int k0 = 0; k0 < 256; k0 += 32) {
    __syncthreads();
    float4 av = *(const float4*)(A + (b0 + bb) * 256 + k0 + q * 4);
    A_s[q * 4 + 0][bb] = av.x;
    A_s[q * 4 + 1][bb] = av.y;
    A_s[q * 4 + 2][bb] = av.z;
    A_s[q * 4 + 3][bb] = av.w;
    if (tid < 128) {
      int nl = tid >> 3, qq = tid & 7;
      float4 wv = *(const float4*)(Wq + (n0 + nl) * 256 + k0 + qq * 4);
      W_s[nl][qq * 4 + 0] = wv.x;
      W_s[nl][qq * 4 + 1] = wv.y;
      W_s[nl][qq * 4 + 2] = wv.z;
      W_s[nl][qq * 4 + 3] = wv.w;
    }
    __syncthreads();
#pragma unroll
    for (int kk = 0; kk < 32; ++kk) {
      float a0 = A_s[kk][2 * br];
      float a1 = A_s[kk][2 * br + 1];
      float w = W_s[n][kk];
      acc0 += a0 * w;
      acc1 += a1 * w;
    }
  }
  C[(b0 + 2 * br) * 256 + n0 + n] = acc0;
  C[(b0 + 2 * br + 1) * 256 + n0 + n] = acc1;
}

// -------------------------------------------------------- glimpse attention
// 1 batch per block, 256 threads. threads 0..127: l-index, h in [0,128);
// threads 128..255: same l, h in [128,256). e_t layout [b][l][h].
__global__ __launch_bounds__(256) void glimpse_kernel(
    const float* __restrict__ qp, const float* __restrict__ v,
    const float* __restrict__ e_t, int* __restrict__ mask,
    const int* __restrict__ prev, float* __restrict__ gl, int step) {
  const int tid = threadIdx.x;
  const int b = blockIdx.x;
  const int li = tid & 127;
  const int half = tid >> 7;
  __shared__ float qp_s[256], v_s[256];
  __shared__ float logit_s[128];
  __shared__ float p_s[128];
  __shared__ float wred_m[2], wred_s[2];
  qp_s[tid] = qp[b * 256 + tid];
  v_s[tid] = v[tid];
  __syncthreads();
  float part = 0.0f;
  if (li < Ln) {
    const float4* ep = (const float4*)(e_t + ((size_t)b * Ln + li) * Hn + half * 128);
    const float4* qp4 = (const float4*)(qp_s + half * 128);
    const float4* v4 = (const float4*)(v_s + half * 128);
#pragma unroll 8
    for (int j = 0; j < 32; ++j) {
      float4 ev = ep[j];
      float4 qv = qp4[j];
      float4 vv = v4[j];
      part += vv.x * fast_tanh(qv.x + ev.x);
      part += vv.y * fast_tanh(qv.y + ev.y);
      part += vv.z * fast_tanh(qv.z + ev.z);
      part += vv.w * fast_tanh(qv.w + ev.w);
    }
  }
  if (half == 1) logit_s[li] = part;
  __syncthreads();
  float lgv = -INFINITY;
  if (half == 0 && li < Ln) {
    float a = part + logit_s[li];
    int pb = prev[b];
    int m = mask[b * Ln + li];
    if (step == 0) {
      if (li == 0) m = 1;
    } else {
      if (step == 1 && li == 0) m = 0;
      if (li == pb) m = 1;
    }
    mask[b * Ln + li] = m;  // pointer-phase apply_mask is idempotent on this
    lgv = m ? -INFINITY : a;
  }
  float wm = wave_max((tid < 128) ? lgv : -INFINITY);
  if (tid < 128 && (tid & 63) == 0) wred_m[tid >> 6] = wm;
  __syncthreads();
  float mx = fmaxf(wred_m[0], wred_m[1]);
  float pvv = (lgv == -INFINITY) ? 0.0f : __expf(lgv - mx);
  float wsm = wave_sum((tid < 128) ? pvv : 0.0f);
  if (tid < 128 && (tid & 63) == 0) wred_s[tid >> 6] = wsm;
  __syncthreads();
  float tot = wred_s[0] + wred_s[1];
  if (tid < 128) p_s[li] = pvv / tot;
  __syncthreads();
  // readout: gl[b,h] = sum_l e_t[b,l,h] * p[l]   (lanes h: coalesced)
  {
    const int h = tid;
    const float* eb = e_t + (size_t)b * Ln * Hn + h;
    float a = 0.0f;
#pragma unroll 4
    for (int l = 0; l < Ln; ++l) a += eb[(size_t)l * Hn] * p_s[l];
    gl[b * Hn + h] = a;
  }
}

// -------------------------------------------------------- pointer attention
__global__ __launch_bounds__(256) void pointer_kernel(
    const float* __restrict__ qp, const float* __restrict__ v,
    const float* __restrict__ e_t, const int* __restrict__ mask,
    int* __restrict__ prev, const float* __restrict__ emb,
    float* __restrict__ xout, float* __restrict__ out, int step) {
  const int tid = threadIdx.x;
  const int b = blockIdx.x;
  const int li = tid & 127;
  const int half = tid >> 7;
  __shared__ float qp_s[256], v_s[256];
  __shared__ float logit_s[128];
  __shared__ float wred_m[2], wred_s[2];
  __shared__ float wval[2];
  __shared__ int widx[2];
  __shared__ int sel_s;
  qp_s[tid] = qp[b * 256 + tid];
  v_s[tid] = v[tid];
  __syncthreads();
  float part = 0.0f;
  if (li < Ln) {
    const float4* ep = (const float4*)(e_t + ((size_t)b * Ln + li) * Hn + half * 128);
    const float4* qp4 = (const float4*)(qp_s + half * 128);
    const float4* v4 = (const float4*)(v_s + half * 128);
#pragma unroll 8
    for (int j = 0; j < 32; ++j) {
      float4 ev = ep[j];
      float4 qv = qp4[j];
      float4 vv = v4[j];
      part += vv.x * fast_tanh(qv.x + ev.x);
      part += vv.y * fast_tanh(qv.y + ev.y);
      part += vv.z * fast_tanh(qv.z + ev.z);
      part += vv.w * fast_tanh(qv.w + ev.w);
    }
  }
  if (half == 1) logit_s[li] = part;
  __syncthreads();
  float lgv = -INFINITY;
  if (half == 0 && li < Ln) {
    float a = part + logit_s[li];
    float lp = 10.0f * fast_tanh(a);
    int m = mask[b * Ln + li];  // glimpse already applied this step's update
    lgv = m ? -INFINITY : lp;
  }
  float wm = wave_max((tid < 128) ? lgv : -INFINITY);
  if (tid < 128 && (tid & 63) == 0) wred_m[tid >> 6] = wm;
  __syncthreads();
  float mx = fmaxf(wred_m[0], wred_m[1]);
  float pvv = (lgv == -INFINITY) ? 0.0f : __expf(lgv - mx);
  float wsm = wave_sum((tid < 128) ? pvv : 0.0f);
  if (tid < 128 && (tid & 63) == 0) wred_s[tid >> 6] = wsm;
  __syncthreads();
  float tot = wred_s[0] + wred_s[1];
  float p = pvv / tot;
  if (half == 0 && li < Ln) out[((size_t)step * Bn + b) * Ln + li] = p;
  // argmax over p, first-index tie-break (threads 0..127 = waves 0,1)
  float val = (tid < 128 && li < Ln) ? p : -1.0f;
  int idx = li;
#pragma unroll
  for (int off = 32; off > 0; off >>= 1) {
    float ov = __shfl_down(val, off, 64);
    int oi = __shfl_down(idx, off, 64);
    if (ov > val || (ov == val && oi < idx)) { val = ov; idx = oi; }
  }
  if (tid < 128 && (tid & 63) == 0) { wval[tid >> 6] = val; widx[tid >> 6] = idx; }
  __syncthreads();
  if (tid == 0) {
    int sel = (wval[1] > wval[0] || (wval[1] == wval[0] && widx[1] < widx[0]))
                  ? widx[1] : widx[0];
    sel_s = sel;
    prev[b] = sel;
    out[(size_t)Tn * Bn * Ln + (size_t)step * Bn + b] = (float)sel;
  }
  __syncthreads();
  int sel = sel_s;
  xout[b * En + tid] = emb[((size_t)sel * Bn + b) * En + tid];
}

// ---------------------------------------------------------------- finalize
__global__ void finalize_kernel(const float* __restrict__ h,
                                const float* __restrict__ c,
                                float* __restrict__ out) {
  int i = blockIdx.x * 256 + threadIdx.x;
  const size_t base = (size_t)Tn * Bn * Ln + (size_t)Tn * Bn;
  if (i < Bn * Hn) {
    out[base + i] = h[i];
    out[base + (size_t)Bn * Hn + i] = c[i];
  }
}

}  // namespace

extern "C" void kernel_launch(void* const* d_in, const int* in_sizes, int n_in,
                              void* d_out, int out_size, void* d_ws, size_t ws_size,
                              hipStream_t stream) {
  (void)in_sizes; (void)n_in; (void)out_size; (void)ws_size;
  const float* dec   = (const float*)d_in[0];
  const float* emb   = (const float*)d_in[1];
  const float* h0    = (const float*)d_in[2];
  const float* c0    = (const float*)d_in[3];
  const float* ctx   = (const float*)d_in[4];
  const float* Wi    = (const float*)d_in[5];
  const float* bi    = (const float*)d_in[6];
  const float* Wh    = (const float*)d_in[7];
  const float* bh    = (const float*)d_in[8];
  const float* gWq   = (const float*)d_in[9];
  const float* gbq   = (const float*)d_in[10];
  const float* gWref = (const float*)d_in[11];
  const float* gbref = (const float*)d_in[12];
  const float* gv    = (const float*)d_in[13];
  const float* pWq   = (const float*)d_in[14];
  const float* pbq   = (const float*)d_in[15];
  const float* pWref = (const float*)d_in[16];
  const float* pbref = (const float*)d_in[17];
  const float* pv    = (const float*)d_in[18];

  float* ws = (float*)d_ws;
  float* e_g   = ws;  ws += (size_t)Bn * Hn * Ln;   // [b][l][h]
  float* e_p   = ws;  ws += (size_t)Bn * Hn * Ln;   // [b][l][h]
  float* WTg   = ws;  ws += 256 * 256;
  float* WTp   = ws;  ws += 256 * 256;
  float* xbuf  = ws;  ws += Bn * En;
  float* hbuf  = ws;  ws += 2 * Bn * Hn;
  float* cbuf  = ws;  ws += 2 * Bn * Hn;
  float* qpg   = ws;  ws += Bn * Hn;
  float* qpp   = ws;  ws += Bn * Hn;
  float* glbuf = ws;  ws += Bn * Hn;
  int* maskb   = (int*)ws;  ws += Bn * Ln;
  int* prevb   = (int*)ws;  ws += Bn;
  float* out = (float*)d_out;

  init_kernel<<<512, 256, 0, stream>>>(dec, h0, c0, xbuf, hbuf, cbuf, maskb, prevb);
  transpose256_kernel<<<256, 256, 0, stream>>>(gWref, WTg);
  transpose256_kernel<<<256, 256, 0, stream>>>(pWref, WTp);
  precompute_e_kernel<<<dim3(512, 4), 256, 0, stream>>>(WTg, gbref, ctx, e_g);
  precompute_e_kernel<<<dim3(512, 4), 256, 0, stream>>>(WTp, pbref, ctx, e_p);

  for (int t = 0; t < Tn; ++t) {
    const float* hin = hbuf + (t & 1) * Bn * Hn;
    float* hout      = hbuf + ((t + 1) & 1) * Bn * Hn;
    const float* cin = cbuf + (t & 1) * Bn * Hn;
    float* cout      = cbuf + ((t + 1) & 1) * Bn * Hn;
    lstm_kernel<<<dim3(16, 16), 256, 0, stream>>>(xbuf, hin, cin, Wi, Wh, bi, bh, hout, cout);
    qp_gemm_kernel<<<dim3(16, 16), 256, 0, stream>>>(hout, gWq, gbq, qpg);
    glimpse_kernel<<<512, 256, 0, stream>>>(qpg, gv, e_g, maskb, prevb, glbuf, t);
    qp_gemm_kernel<<<dim3(16, 16), 256, 0, stream>>>(glbuf, pWq, pbq, qpp);
    pointer_kernel<<<512, 256, 0, stream>>>(qpp, pv, e_p, maskb, prevb, emb, xbuf, out, t);
  }
  finalize_kernel<<<512, 256, 0, stream>>>(hbuf, cbuf, out);
}

// Round 3
// 8001.314 us; speedup vs baseline: 2.8820x; 1.1849x over previous
//
#include <hip/hip_runtime.h>
#include <math.h>

namespace {

constexpr int Bn = 512;
constexpr int Ln = 100;
constexpr int En = 256;
constexpr int Hn = 256;
constexpr int Tn = 100;

// fast tanh: sign(x) * (1 - e^{-2|x|}) / (1 + e^{-2|x|});  ~3e-8 abs error
__device__ __forceinline__ float fast_tanh(float x) {
  float ax = fabsf(x);
  float e = __expf(-2.0f * ax);
  float t = (1.0f - e) / (1.0f + e);
  return copysignf(t, x);
}
__device__ __forceinline__ float fast_sigm(float x) {
  return 1.0f / (1.0f + __expf(-x));
}

__device__ __forceinline__ float wave_max(float v) {
#pragma unroll
  for (int off = 32; off > 0; off >>= 1) v = fmaxf(v, __shfl_xor(v, off, 64));
  return v;
}
__device__ __forceinline__ float wave_sum(float v) {
#pragma unroll
  for (int off = 32; off > 0; off >>= 1) v += __shfl_xor(v, off, 64);
  return v;
}

// ---------------------------------------------------------------- init
__global__ void init_kernel(const float* __restrict__ dec, const float* __restrict__ h0,
                            const float* __restrict__ c0, float* __restrict__ x,
                            float* __restrict__ h, float* __restrict__ c,
                            int* __restrict__ mask, int* __restrict__ prev) {
  int i = blockIdx.x * 256 + threadIdx.x;
  if (i < Bn * En) x[i] = dec[i];
  if (i < Bn * Hn) { h[i] = h0[i]; c[i] = c0[i]; }
  if (i < Bn * Ln) mask[i] = 0;
  if (i < Bn) prev[i] = 0;
}

// ------------------------------------------------------- 256x256 transpose
__global__ void transpose256_kernel(const float* __restrict__ W, float* __restrict__ WT) {
  int h = blockIdx.x, k = threadIdx.x;
  WT[k * 256 + h] = W[h * 256 + k];
}

// ----------------------------------------------- M = pWq @ gWref  (256x256)
__global__ void matmul_M_kernel(const float* __restrict__ pWq,
                                const float* __restrict__ gWref,
                                float* __restrict__ M) {
  int i = blockIdx.x, j = threadIdx.x;
  float acc = 0.0f;
  for (int h = 0; h < 256; ++h) acc += pWq[i * 256 + h] * gWref[h * 256 + j];
  M[i * 256 + j] = acc;
}

// ----------------------------------------------- mb = pWq @ gbref  (256)
__global__ void mb_kernel(const float* __restrict__ pWq,
                          const float* __restrict__ gbref,
                          float* __restrict__ mb) {
  __shared__ float gb[256];
  int i = threadIdx.x;
  gb[i] = gbref[i];
  __syncthreads();
  float acc = 0.0f;
  for (int h = 0; h < 256; ++h) acc += pWq[i * 256 + h] * gb[h];
  mb[i] = acc;
}

// ------------------------------------------------- e_t[b][l][h] = (W @ ctx)[b,h,l] + bref[h]
__global__ __launch_bounds__(256) void precompute_e_kernel(
    const float* __restrict__ WT, const float* __restrict__ bref,
    const float* __restrict__ context, float* __restrict__ e_t) {
  int b = blockIdx.x;           // 0..511
  int l0 = blockIdx.y * 25;     // 4 chunks of 25
  int h = threadIdx.x;          // 0..255
  __shared__ float ctx_s[25][256];
  for (int li = 0; li < 25; ++li)
    ctx_s[li][h] = context[((size_t)(l0 + li) * Bn + b) * Hn + h];
  __syncthreads();
  float acc[25];
  float bias = bref[h];
#pragma unroll
  for (int li = 0; li < 25; ++li) acc[li] = bias;
  for (int k = 0; k < 256; ++k) {
    float w = WT[k * 256 + h];
#pragma unroll
    for (int li = 0; li < 25; ++li) acc[li] += w * ctx_s[li][k];
  }
#pragma unroll
  for (int li = 0; li < 25; ++li)
    e_t[((size_t)b * Ln + (l0 + li)) * Hn + h] = acc[li];   // lanes h: coalesced
}

// ------------------------------------------- LSTM gates GEMM + cell update
__global__ __launch_bounds__(256) void lstm_kernel(
    const float* __restrict__ x, const float* __restrict__ h_in,
    const float* __restrict__ c_in, const float* __restrict__ Wi,
    const float* __restrict__ Wh, const float* __restrict__ bi,
    const float* __restrict__ bh, float* __restrict__ h_out,
    float* __restrict__ c_out) {
  const int b0 = blockIdx.x * 32;
  const int n0 = blockIdx.y * 16;
  const int tid = threadIdx.x;
  const int n = tid & 15;
  const int br = tid >> 4;
  __shared__ float A_s[32][33];
  __shared__ float W_s[4][16][33];
  float acc[4][2];
  const int nn = n0 + n;
#pragma unroll
  for (int g = 0; g < 4; ++g) {
    float bias = bi[g * 256 + nn] + bh[g * 256 + nn];
    acc[g][0] = bias;
    acc[g][1] = bias;
  }
  const int bb = tid >> 3, q = tid & 7;
  for (int k0 = 0; k0 < 512; k0 += 32) {
    const float* Asrc = (k0 < 256) ? x : h_in;
    const float* Wsrc = (k0 < 256) ? Wi : Wh;
    const int kb = k0 & 255;
    __syncthreads();
    float4 av = *(const float4*)(Asrc + (b0 + bb) * 256 + kb + q * 4);
    A_s[q * 4 + 0][bb] = av.x;
    A_s[q * 4 + 1][bb] = av.y;
    A_s[q * 4 + 2][bb] = av.z;
    A_s[q * 4 + 3][bb] = av.w;
#pragma unroll
    for (int s = 0; s < 2; ++s) {
      int sl = tid + s * 256;
      int g = sl >> 7;
      int nl = (sl >> 3) & 15;
      int qq = sl & 7;
      float4 wv = *(const float4*)(Wsrc + ((g * 256 + n0 + nl) * 256) + kb + qq * 4);
      W_s[g][nl][qq * 4 + 0] = wv.x;
      W_s[g][nl][qq * 4 + 1] = wv.y;
      W_s[g][nl][qq * 4 + 2] = wv.z;
      W_s[g][nl][qq * 4 + 3] = wv.w;
    }
    __syncthreads();
#pragma unroll
    for (int kk = 0; kk < 32; ++kk) {
      float a0 = A_s[kk][2 * br];
      float a1 = A_s[kk][2 * br + 1];
#pragma unroll
      for (int g = 0; g < 4; ++g) {
        float w = W_s[g][n][kk];
        acc[g][0] += a0 * w;
        acc[g][1] += a1 * w;
      }
    }
  }
#pragma unroll
  for (int m = 0; m < 2; ++m) {
    int b = b0 + 2 * br + m;
    float ig = acc[0][m], fg = acc[1][m], cg = acc[2][m], og = acc[3][m];
    float cold = c_in[b * 256 + nn];
    float cy = fast_sigm(fg) * cold + fast_sigm(ig) * fast_tanh(cg);
    float hy = fast_sigm(og) * fast_tanh(cy);
    c_out[b * 256 + nn] = cy;
    h_out[b * 256 + nn] = hy;
  }
}

// ---------------------------------------------------- qp = A @ Wq^T + bq
__global__ __launch_bounds__(256) void qp_gemm_kernel(
    const float* __restrict__ A, const float* __restrict__ Wq,
    const float* __restrict__ bq, float* __restrict__ C) {
  const int b0 = blockIdx.x * 32;
  const int n0 = blockIdx.y * 16;
  const int tid = threadIdx.x;
  const int n = tid & 15;
  const int br = tid >> 4;
  __shared__ float A_s[32][33];
  __shared__ float W_s[16][33];
  float bias = bq[n0 + n];
  float acc0 = bias, acc1 = bias;
  const int bb = tid >> 3, q = tid & 7;
  for (int k0 = 0; k0 < 256; k0 += 32) {
    __syncthreads();
    float4 av = *(const float4*)(A + (b0 + bb) * 256 + k0 + q * 4);
    A_s[q * 4 + 0][bb] = av.x;
    A_s[q * 4 + 1][bb] = av.y;
    A_s[q * 4 + 2][bb] = av.z;
    A_s[q * 4 + 3][bb] = av.w;
    if (tid < 128) {
      int nl = tid >> 3, qq = tid & 7;
      float4 wv = *(const float4*)(Wq + (n0 + nl) * 256 + k0 + qq * 4);
      W_s[nl][qq * 4 + 0] = wv.x;
      W_s[nl][qq * 4 + 1] = wv.y;
      W_s[nl][qq * 4 + 2] = wv.z;
      W_s[nl][qq * 4 + 3] = wv.w;
    }
    __syncthreads();
#pragma unroll
    for (int kk = 0; kk < 32; ++kk) {
      float a0 = A_s[kk][2 * br];
      float a1 = A_s[kk][2 * br + 1];
      float w = W_s[n][kk];
      acc0 += a0 * w;
      acc1 += a1 * w;
    }
  }
  C[(b0 + 2 * br) * 256 + n0 + n] = acc0;
  C[(b0 + 2 * br + 1) * 256 + n0 + n] = acc1;
}

// ---------------------------------- fused: glimpse + qp_p(via f_p) + pointer
// 1 batch per block, 256 threads. li = tid&127, half = tid>>7.
__global__ __launch_bounds__(256) void attn_fused_kernel(
    const float* __restrict__ qp_g, const float* __restrict__ gv,
    const float* __restrict__ pv, const float* __restrict__ pbq,
    const float* __restrict__ e_g, const float* __restrict__ f_p,
    const float* __restrict__ e_p, int* __restrict__ mask,
    int* __restrict__ prev, const float* __restrict__ emb,
    float* __restrict__ xout, float* __restrict__ out, int step) {
  const int tid = threadIdx.x;
  const int b = blockIdx.x;
  const int li = tid & 127;
  const int half = tid >> 7;
  __shared__ float q1_s[256], vg_s[256], vp_s[256], q2_s[256];
  __shared__ float logit_s[128], p_s[128];
  __shared__ float wred_m[2], wred_s[2];
  __shared__ float wval[2];
  __shared__ int widx[2];
  __shared__ int sel_s;
  q1_s[tid] = qp_g[b * 256 + tid];
  vg_s[tid] = gv[tid];
  vp_s[tid] = pv[tid];
  __syncthreads();
  // ---------------- glimpse logits
  float part = 0.0f;
  if (li < Ln) {
    const float4* ep = (const float4*)(e_g + ((size_t)b * Ln + li) * Hn + half * 128);
    const float4* q4 = (const float4*)(q1_s + half * 128);
    const float4* v4 = (const float4*)(vg_s + half * 128);
#pragma unroll 8
    for (int j = 0; j < 32; ++j) {
      float4 ev = ep[j];
      float4 qv = q4[j];
      float4 vv = v4[j];
      part += vv.x * fast_tanh(qv.x + ev.x);
      part += vv.y * fast_tanh(qv.y + ev.y);
      part += vv.z * fast_tanh(qv.z + ev.z);
      part += vv.w * fast_tanh(qv.w + ev.w);
    }
  }
  if (half == 1) logit_s[li] = part;
  __syncthreads();
  float lgv = -INFINITY;
  int mreg = 1;
  if (half == 0 && li < Ln) {
    float a = part + logit_s[li];
    int pb = prev[b];
    int m = mask[b * Ln + li];
    if (step == 0) {
      if (li == 0) m = 1;
    } else {
      if (step == 1 && li == 0) m = 0;
      if (li == pb) m = 1;
    }
    mask[b * Ln + li] = m;   // single update per step; pointer-phase apply_mask is idempotent
    mreg = m;
    lgv = m ? -INFINITY : a;
  }
  // ---------------- glimpse softmax -> p_s
  float wm = wave_max((tid < 128) ? lgv : -INFINITY);
  if (tid < 128 && (tid & 63) == 0) wred_m[tid >> 6] = wm;
  __syncthreads();
  float mx = fmaxf(wred_m[0], wred_m[1]);
  float pvv = (lgv == -INFINITY) ? 0.0f : __expf(lgv - mx);
  float wsm = wave_sum((tid < 128) ? pvv : 0.0f);
  if (tid < 128 && (tid & 63) == 0) wred_s[tid >> 6] = wsm;
  __syncthreads();
  float tot = wred_s[0] + wred_s[1];
  if (tid < 128) p_s[li] = pvv / tot;     // 0 for li >= Ln (pvv==0)
  __syncthreads();
  // ---------------- qp_p[h'] = pbq[h'] + sum_l p[l] * f_p[b,l,h']
  {
    float acc = pbq[tid];
    const float* fb = f_p + (size_t)b * Ln * Hn + tid;
#pragma unroll 4
    for (int l = 0; l < Ln; ++l) acc += p_s[l] * fb[(size_t)l * Hn];
    q2_s[tid] = acc;
  }
  __syncthreads();
  // ---------------- pointer logits
  part = 0.0f;
  if (li < Ln) {
    const float4* ep = (const float4*)(e_p + ((size_t)b * Ln + li) * Hn + half * 128);
    const float4* q4 = (const float4*)(q2_s + half * 128);
    const float4* v4 = (const float4*)(vp_s + half * 128);
#pragma unroll 8
    for (int j = 0; j < 32; ++j) {
      float4 ev = ep[j];
      float4 qv = q4[j];
      float4 vv = v4[j];
      part += vv.x * fast_tanh(qv.x + ev.x);
      part += vv.y * fast_tanh(qv.y + ev.y);
      part += vv.z * fast_tanh(qv.z + ev.z);
      part += vv.w * fast_tanh(qv.w + ev.w);
    }
  }
  if (half == 1) logit_s[li] = part;
  __syncthreads();
  lgv = -INFINITY;
  if (half == 0 && li < Ln) {
    float a = part + logit_s[li];
    float lp = 10.0f * fast_tanh(a);
    lgv = mreg ? -INFINITY : lp;
  }
  // ---------------- pointer softmax + probs + argmax
  wm = wave_max((tid < 128) ? lgv : -INFINITY);
  if (tid < 128 && (tid & 63) == 0) wred_m[tid >> 6] = wm;
  __syncthreads();
  mx = fmaxf(wred_m[0], wred_m[1]);
  pvv = (lgv == -INFINITY) ? 0.0f : __expf(lgv - mx);
  wsm = wave_sum((tid < 128) ? pvv : 0.0f);
  if (tid < 128 && (tid & 63) == 0) wred_s[tid >> 6] = wsm;
  __syncthreads();
  tot = wred_s[0] + wred_s[1];
  float p = pvv / tot;
  if (half == 0 && li < Ln) out[((size_t)step * Bn + b) * Ln + li] = p;
  float val = (tid < 128 && li < Ln) ? p : -1.0f;
  int idx = li;
#pragma unroll
  for (int off = 32; off > 0; off >>= 1) {
    float ov = __shfl_down(val, off, 64);
    int oi = __shfl_down(idx, off, 64);
    if (ov > val || (ov == val && oi < idx)) { val = ov; idx = oi; }
  }
  if (tid < 128 && (tid & 63) == 0) { wval[tid >> 6] = val; widx[tid >> 6] = idx; }
  __syncthreads();
  if (tid == 0) {
    int sel = (wval[1] > wval[0] || (wval[1] == wval[0] && widx[1] < widx[0]))
                  ? widx[1] : widx[0];
    sel_s = sel;
    prev[b] = sel;
    out[(size_t)Tn * Bn * Ln + (size_t)step * Bn + b] = (float)sel;
  }
  __syncthreads();
  int sel = sel_s;
  xout[b * En + tid] = emb[((size_t)sel * Bn + b) * En + tid];
}

// ---------------------------------------------------------------- finalize
__global__ void finalize_kernel(const float* __restrict__ h,
                                const float* __restrict__ c,
                                float* __restrict__ out) {
  int i = blockIdx.x * 256 + threadIdx.x;
  const size_t base = (size_t)Tn * Bn * Ln + (size_t)Tn * Bn;
  if (i < Bn * Hn) {
    out[base + i] = h[i];
    out[base + (size_t)Bn * Hn + i] = c[i];
  }
}

}  // namespace

extern "C" void kernel_launch(void* const* d_in, const int* in_sizes, int n_in,
                              void* d_out, int out_size, void* d_ws, size_t ws_size,
                              hipStream_t stream) {
  (void)in_sizes; (void)n_in; (void)out_size; (void)ws_size;
  const float* dec   = (const float*)d_in[0];
  const float* emb   = (const float*)d_in[1];
  const float* h0    = (const float*)d_in[2];
  const float* c0    = (const float*)d_in[3];
  const float* ctx   = (const float*)d_in[4];
  const float* Wi    = (const float*)d_in[5];
  const float* bi    = (const float*)d_in[6];
  const float* Wh    = (const float*)d_in[7];
  const float* bh    = (const float*)d_in[8];
  const float* gWq   = (const float*)d_in[9];
  const float* gbq   = (const float*)d_in[10];
  const float* gWref = (const float*)d_in[11];
  const float* gbref = (const float*)d_in[12];
  const float* gv    = (const float*)d_in[13];
  const float* pWq   = (const float*)d_in[14];
  const float* pbq   = (const float*)d_in[15];
  const float* pWref = (const float*)d_in[16];
  const float* pbref = (const float*)d_in[17];
  const float* pv    = (const float*)d_in[18];

  float* ws = (float*)d_ws;
  float* e_g   = ws;  ws += (size_t)Bn * Hn * Ln;   // [b][l][h]
  float* e_p   = ws;  ws += (size_t)Bn * Hn * Ln;   // [b][l][h]
  float* f_p   = ws;  ws += (size_t)Bn * Hn * Ln;   // [b][l][h']  (pWq @ e_g)
  float* WTg   = ws;  ws += 256 * 256;
  float* WTp   = ws;  ws += 256 * 256;
  float* Mbuf  = ws;  ws += 256 * 256;
  float* MT    = ws;  ws += 256 * 256;
  float* mb    = ws;  ws += 256;
  float* xbuf  = ws;  ws += Bn * En;
  float* hbuf  = ws;  ws += 2 * Bn * Hn;
  float* cbuf  = ws;  ws += 2 * Bn * Hn;
  float* qpg   = ws;  ws += Bn * Hn;
  int* maskb   = (int*)ws;  ws += Bn * Ln;
  int* prevb   = (int*)ws;  ws += Bn;
  float* out = (float*)d_out;

  init_kernel<<<512, 256, 0, stream>>>(dec, h0, c0, xbuf, hbuf, cbuf, maskb, prevb);
  transpose256_kernel<<<256, 256, 0, stream>>>(gWref, WTg);
  transpose256_kernel<<<256, 256, 0, stream>>>(pWref, WTp);
  matmul_M_kernel<<<256, 256, 0, stream>>>(pWq, gWref, Mbuf);
  mb_kernel<<<1, 256, 0, stream>>>(pWq, gbref, mb);
  transpose256_kernel<<<256, 256, 0, stream>>>(Mbuf, MT);
  precompute_e_kernel<<<dim3(512, 4), 256, 0, stream>>>(WTg, gbref, ctx, e_g);
  precompute_e_kernel<<<dim3(512, 4), 256, 0, stream>>>(WTp, pbref, ctx, e_p);
  precompute_e_kernel<<<dim3(512, 4), 256, 0, stream>>>(MT, mb, ctx, f_p);

  for (int t = 0; t < Tn; ++t) {
    const float* hin = hbuf + (t & 1) * Bn * Hn;
    float* hout      = hbuf + ((t + 1) & 1) * Bn * Hn;
    const float* cin = cbuf + (t & 1) * Bn * Hn;
    float* cout      = cbuf + ((t + 1) & 1) * Bn * Hn;
    lstm_kernel<<<dim3(16, 16), 256, 0, stream>>>(xbuf, hin, cin, Wi, Wh, bi, bh, hout, cout);
    qp_gemm_kernel<<<dim3(16, 16), 256, 0, stream>>>(hout, gWq, gbq, qpg);
    attn_fused_kernel<<<512, 256, 0, stream>>>(qpg, gv, pv, pbq, e_g, f_p, e_p,
                                               maskb, prevb, emb, xbuf, out, t);
  }
  finalize_kernel<<<512, 256, 0, stream>>>(hbuf, cbuf, out);
}